// Round 12
// baseline (92.707 us; speedup 1.0000x reference)
//
#include <hip/hip_runtime.h>

// CMDNet (M=2, m={-1,+1}, equal alpha) — MFMA HH + dot2/DPP matvec,
// slim-footprint edition targeting 8 waves/SIMD.
//
// R4/R6/R10/R11 pattern: every non-spilling variant pinned at ~36% occupancy
// (3 waves/SIMD) because total regs (VGPR + 16 AGPR acc) > 64 -> next
// occupancy tier lost (m69 quantization). Spilled variants proved 65-80% is
// reachable. This version is engineered to fit <=64 TOTAL regs:
//  - ONE hhbuf LDS region (16 KB): PASS0 -> store -> PASS1 -> gatherA
//    (region still batch0) -> store -> gatherB -> uniform cndmask combine.
//    No divergent long-lived defs (R10 lesson), LDS 18 KB -> 8 blocks/CU.
//  - peak regs ~56: staging(~40 VGPR)+acc(16 AGPR) in PASS1; gA(16)+acc(16)
//    +misc during gathers; loop needs own_pk(16)+state(~14).
// Tripwire: FETCH >> 68 MB or WRITE >> 6 MB => 4th spill => revert to (256,6).
//
// Loop (numerics proven R10/R11, absmax = bf16 output quantum):
//  v_dot2_f32_f16 matvec on packed f16 (0.5 prefolded), xor-16 via
//  __builtin_amdgcn_permlane16_swap ((A+B)-x recovery, direction-robust),
//  exp2-domain G. Phase 1: v_mfma_f32_32x32x16_bf16, bf16 hi/lo split
//  (err ~2^-17), ONE 16-AGPR acc reused for both batches; yH VALU partials.

#define NRX 64
#define KSYM 32

typedef float  f32x16 __attribute__((ext_vector_type(16)));
typedef short  short8 __attribute__((ext_vector_type(8)));
typedef _Float16 h16x2 __attribute__((ext_vector_type(2)));

__device__ __forceinline__ float readlane_f(float v, int lane) {
    return __int_as_float(__builtin_amdgcn_readlane(__float_as_int(v), lane));
}
__device__ __forceinline__ unsigned cvt_pk_bf16(float a, float b) {
    unsigned r;
    asm("v_cvt_pk_bf16_f32 %0, %1, %2" : "=v"(r) : "v"(a), "v"(b));
    return r;
}
__device__ __forceinline__ int cvt_pk_f16(float a, float b) {  // RTZ pack
    int r;
    asm("v_cvt_pkrtz_f16_f32 %0, %1, %2" : "=v"(r) : "v"(a), "v"(b));
    return r;
}
template <int N>
__device__ __forceinline__ int dpp_ror_i(int v) {
    return __builtin_amdgcn_update_dpp(0, v, 0x120 + N, 0xF, 0xF, true);
}
__device__ __forceinline__ float dot2_f16(int a, int b, float c) {
#if __has_builtin(__builtin_amdgcn_fdot2)
    union { int i; h16x2 h; } ua, ub;
    ua.i = a; ub.i = b;
    return __builtin_amdgcn_fdot2(ua.h, ub.h, c, false);
#else
    float r = c;
    asm("v_dot2_f32_f16 %0, %1, %2, %0" : "+v"(r) : "v"(a), "v"(b));
    return r;
#endif
}
__device__ __forceinline__ float exp2_fast(float x) {
#if __has_builtin(__builtin_amdgcn_exp2f)
    return __builtin_amdgcn_exp2f(x);
#else
    float r; asm("v_exp_f32 %0, %1" : "=v"(r) : "v"(x)); return r;
#endif
}
__device__ __forceinline__ float xor16_f(float x) {
#if __has_builtin(__builtin_amdgcn_permlane16_swap)
    typedef unsigned uint2v __attribute__((ext_vector_type(2)));
    unsigned xi = __float_as_int(x);
    uint2v pr = __builtin_amdgcn_permlane16_swap(xi, xi, false, false);
    return (__uint_as_float(pr[0]) + __uint_as_float(pr[1])) - x;
#else
    return __int_as_float(
        __builtin_amdgcn_ds_swizzle(__float_as_int(x), 0x401F)); // xor 16
#endif
}

union FragU { unsigned u[4]; short8 s; };

__global__ __launch_bounds__(256, 8) void cmdnet_kernel(
    const float* __restrict__ yt,      // [B,64]
    const float* __restrict__ Ht,      // [B,64,32]
    const float* __restrict__ sigmat0, // [B]
    const float* __restrict__ taui,    // [niter+1]
    const float* __restrict__ delta,   // [niter]
    float* __restrict__ out_ft,        // [B,32,2]
    float* __restrict__ out_xt,        // [B,32]
    int niter)
{
    __shared__ __align__(16) float hhbuf[4][KSYM * KSYM]; // 16 KB: ONE region/wave
    __shared__ __align__(16) float ytL[4][2][NRX];        // 2 KB

    const int tid  = threadIdx.x;
    const int w    = tid >> 6;
    const int lane = tid & 63;
    const int k    = lane & 31;
    const int h    = lane >> 5;
    const int hi8  = h * 8;
    const int bb   = blockIdx.x * 8 + w * 2;
    const int b    = bb + h;
    const float LOG2E = 1.4426950408889634f;

    ytL[w][0][lane] = yt[(size_t)bb * NRX + lane];
    ytL[w][1][lane] = yt[(size_t)bb * NRX + NRX + lane];

    float dreg = 0.f, treg = 1.f;
    if (lane < niter) { dreg = delta[lane] * LOG2E; treg = fabsf(taui[lane + 1]); }

    float sig2 = sigmat0[b];
    sig2 *= sig2;

    float yhp0 = 0.f, yhp1 = 0.f;
    f32x16 acc;

    // ---- MFMA pass over batch S: acc = HH_S (bf16 hi/lo split), yH partial ----
    #define MFMA_PASS(S, YHP) do {                                             \
        _Pragma("unroll")                                                      \
        for (int j = 0; j < 16; ++j) acc[j] = 0.f;                             \
        const float* Hb = Ht + ((size_t)(bb + (S))) * (NRX * KSYM);            \
        _Pragma("unroll")                                                      \
        for (int c = 0; c < 4; ++c) {                                          \
            const float* base = Hb + (c * 16 + hi8) * KSYM + k;                \
            float f[8];                                                        \
            _Pragma("unroll")                                                  \
            for (int e = 0; e < 8; ++e) f[e] = base[e * KSYM];                 \
            float4 ya = *reinterpret_cast<const float4*>(&ytL[w][S][c*16+hi8]);\
            float4 yb = *reinterpret_cast<const float4*>(&ytL[w][S][c*16+hi8+4]);\
            YHP = fmaf(ya.x, f[0], YHP); YHP = fmaf(ya.y, f[1], YHP);          \
            YHP = fmaf(ya.z, f[2], YHP); YHP = fmaf(ya.w, f[3], YHP);          \
            YHP = fmaf(yb.x, f[4], YHP); YHP = fmaf(yb.y, f[5], YHP);          \
            YHP = fmaf(yb.z, f[6], YHP); YHP = fmaf(yb.w, f[7], YHP);          \
            FragU hiF, loF;                                                    \
            _Pragma("unroll")                                                  \
            for (int p = 0; p < 4; ++p) {                                      \
                unsigned hp = cvt_pk_bf16(f[2*p], f[2*p+1]);                   \
                float h0 = __uint_as_float(hp << 16);                          \
                float h1 = __uint_as_float(hp & 0xffff0000u);                  \
                loF.u[p] = cvt_pk_bf16(f[2*p] - h0, f[2*p+1] - h1);            \
                hiF.u[p] = hp;                                                 \
            }                                                                  \
            acc = __builtin_amdgcn_mfma_f32_32x32x16_bf16(hiF.s, hiF.s, acc, 0,0,0); \
            acc = __builtin_amdgcn_mfma_f32_32x32x16_bf16(hiF.s, loF.s, acc, 0,0,0); \
            acc = __builtin_amdgcn_mfma_f32_32x32x16_bf16(loF.s, hiF.s, acc, 0,0,0); \
        }                                                                      \
    } while (0)

    // acc -> LDS (C/D layout: col=lane&31, row=(j&3)+8*(j>>2)+4*h)
    #define STORE_ACC() do {                                                   \
        _Pragma("unroll")                                                      \
        for (int j = 0; j < 16; ++j) {                                         \
            int row = (j & 3) + 8 * (j >> 2) + 4 * h;                          \
            hhbuf[w][row * 32 + k] = acc[j];                                   \
        }                                                                      \
    } while (0)

    // uniform diagonal-permuted gather (same dpp ctrl as the loop), 0.5-scaled
    #define GATHER(DST) do {                                                   \
        const float* rowp = &hhbuf[w][k * 32];                                 \
        const int low4 = k & 15;                                               \
        DST[0] = cvt_pk_f16(0.5f * rowp[k], 0.5f * rowp[k ^ 16]);              \
        GATH(DST, 1)  GATH(DST, 2)  GATH(DST, 3)  GATH(DST, 4)  GATH(DST, 5)  \
        GATH(DST, 6)  GATH(DST, 7)  GATH(DST, 8)  GATH(DST, 9)  GATH(DST, 10) \
        GATH(DST, 11) GATH(DST, 12) GATH(DST, 13) GATH(DST, 14) GATH(DST, 15) \
    } while (0)
    #define GATH(DST, J) {                                                     \
        int idx = dpp_ror_i<J>(low4);                                          \
        DST[J] = cvt_pk_f16(0.5f * rowp[(k & 16) | idx],                       \
                            0.5f * rowp[((k & 16) ^ 16) | idx]); }

    // ---- Phase 1/2: batch0 -> store -> batch1 -> gatherA -> store -> gatherB
    MFMA_PASS(0, yhp0);
    STORE_ACC();                // region := HH_0
    MFMA_PASS(1, yhp1);         // acc := HH_1 (region still HH_0)
    int gA[16];
    GATHER(gA);                 // batch-0 rows (all lanes, uniform)
    STORE_ACC();                // region := HH_1 (same-wave DS order: after reads)
    int gB[16];
    GATHER(gB);                 // batch-1 rows

    int own_pk[16];
    const bool hs = (h != 0);
    #pragma unroll
    for (int j = 0; j < 16; ++j) own_pk[j] = hs ? gB[j] : gA[j];

    float yh0 = yhp0 + __shfl_xor(yhp0, 32, 64);
    float yh1 = yhp1 + __shfl_xor(yhp1, 32, 64);
    float yh  = 0.5f * (hs ? yh1 : yh0);   // pre-halved to match own_pk scale

    // ---- Phase 3: iterations ----
    float tau = fabsf(taui[0]);
    float Gl0 = 0.f, Gl1 = 0.f;            // G * log2e
    float xt = 0.f;

    for (int i = 0; i < niter; ++i) {
        float d2       = readlane_f(dreg, i);   // delta*log2e
        float tau_next = readlane_f(treg, i);

        float xts = xor16_f(xt);
        int xpk = cvt_pk_f16(xt, xts);

        float a0 = -yh, a1 = 0.f, a2 = 0.f, a3 = 0.f;
        a0 = dot2_f16(own_pk[0], xpk, a0);
        #define STEP(J) {                                                      \
            int xr = dpp_ror_i<J>(xpk);                                        \
            float& aa = ((J) & 3) == 0 ? a0 : ((J) & 3) == 1 ? a1              \
                       : ((J) & 3) == 2 ? a2 : a3;                             \
            aa = dot2_f16(own_pk[J], xr, aa); }
        STEP(1)  STEP(2)  STEP(3)  STEP(4)  STEP(5)
        STEP(6)  STEP(7)  STEP(8)  STEP(9)  STEP(10)
        STEP(11) STEP(12) STEP(13) STEP(14) STEP(15)
        #undef STEP
        float r = (a0 + a1) + (a2 + a3);   // = 0.5*(xHH - yH)

        float t  = fmaf(-xt, xt, 1.0f);
        float p  = tau * t * r;            // = 2*tau*ft0*ft1*(xHH-yH)
        float e0 = exp2_fast(-Gl0);        // = exp(-G0)
        float e1 = exp2_fast(-Gl1);
        float g0 = fmaf(sig2, 1.f - e0, -p);
        float g1 = fmaf(sig2, 1.f - e1,  p);
        Gl0 = fmaf(-d2, g0, Gl0);
        Gl1 = fmaf(-d2, g1, Gl1);

        tau = tau_next;
        float z2 = tau * (Gl1 - Gl0);      // = log2e * z
        float ez = exp2_fast(-fabsf(z2));  // = exp(-|z|)
        float sg = __builtin_amdgcn_rcpf(1.f + ez);
        float m  = (1.f - ez) * sg;        // |tanh(z/2)|
        xt = __builtin_copysignf(m, z2);
    }

    // ---- outputs: ft1 = (1+xt)/2, ft0 = (1-xt)/2 ----
    float ft1 = fmaf(0.5f, xt, 0.5f);
    float ft0 = 1.f - ft1;
    float2 f2 = make_float2(ft0, ft1);
    reinterpret_cast<float2*>(out_ft)[(size_t)b * KSYM + k] = f2;
    out_xt[(size_t)b * KSYM + k] = xt;
}

extern "C" void kernel_launch(void* const* d_in, const int* in_sizes, int n_in,
                              void* d_out, int out_size, void* d_ws, size_t ws_size,
                              hipStream_t stream) {
    const float* yt    = (const float*)d_in[0];
    const float* Ht    = (const float*)d_in[1];
    const float* sg    = (const float*)d_in[2];
    const float* taui  = (const float*)d_in[3];
    const float* delta = (const float*)d_in[4];
    int B     = in_sizes[2];
    int niter = in_sizes[4];
    float* out    = (float*)d_out;
    float* out_ft = out;
    float* out_xt = out + (size_t)B * 64;

    dim3 grid(B / 8), block(256);
    hipLaunchKernelGGL(cmdnet_kernel, grid, block, 0, stream,
                       yt, Ht, sg, taui, delta, out_ft, out_xt, niter);
}

// Round 13
// 81.442 us; speedup vs baseline: 1.1383x; 1.1383x over previous
//
#include <hip/hip_runtime.h>

// CMDNet (M=2, m={-1,+1}, equal alpha) — MFMA HH + dot2/DPP matvec,
// 2-stream ILP edition: one wave owns 4 batches = two independent
// iteration streams interleaved in registers.
//
// R2/R3/R5/R7/R8/R12 (six data points): the allocator never honors
// waves/EU > 4 on this kernel without spilling. (256,4) is final.
// R11 analysis: loop = 86% of VALU work, VALUBusy 67%, ~26us of exposed
// serial-chain latency (3-4 resident waves). Fix: ILP not TLP — stream B's
// matvec issues into stream A's epilogue stalls. Same instruction count,
// half the exposed latency. Grid halves to 1024 blocks.
//
// Numerics (all proven R10/R11, absmax = bf16 output quantum 0.0039):
//  - HH = Ht^T Ht via v_mfma_f32_32x32x16_bf16, bf16 hi/lo split (~2^-17)
//  - ONE 16-AGPR acc + ONE 16KB LDS region reused across all 4 passes;
//    uniform gathers (no divergent long-lived defs — R10 lesson)
//  - loop: v_dot2_f32_f16 on packed f16 (0.5 prefolded), xor-16 via
//    permlane16_swap builtin ((A+B)-x recovery), exp2-domain G.
// Tripwire: FETCH >> 68 MB or WRITE >> 6 MB => spill => drop to 1 stream.

#define NRX 64
#define KSYM 32

typedef float  f32x16 __attribute__((ext_vector_type(16)));
typedef short  short8 __attribute__((ext_vector_type(8)));
typedef _Float16 h16x2 __attribute__((ext_vector_type(2)));

__device__ __forceinline__ float readlane_f(float v, int lane) {
    return __int_as_float(__builtin_amdgcn_readlane(__float_as_int(v), lane));
}
__device__ __forceinline__ unsigned cvt_pk_bf16(float a, float b) {
    unsigned r;
    asm("v_cvt_pk_bf16_f32 %0, %1, %2" : "=v"(r) : "v"(a), "v"(b));
    return r;
}
__device__ __forceinline__ int cvt_pk_f16(float a, float b) {  // RTZ pack
    int r;
    asm("v_cvt_pkrtz_f16_f32 %0, %1, %2" : "=v"(r) : "v"(a), "v"(b));
    return r;
}
template <int N>
__device__ __forceinline__ int dpp_ror_i(int v) {
    return __builtin_amdgcn_update_dpp(0, v, 0x120 + N, 0xF, 0xF, true);
}
__device__ __forceinline__ float dot2_f16(int a, int b, float c) {
#if __has_builtin(__builtin_amdgcn_fdot2)
    union { int i; h16x2 h; } ua, ub;
    ua.i = a; ub.i = b;
    return __builtin_amdgcn_fdot2(ua.h, ub.h, c, false);
#else
    float r = c;
    asm("v_dot2_f32_f16 %0, %1, %2, %0" : "+v"(r) : "v"(a), "v"(b));
    return r;
#endif
}
__device__ __forceinline__ float exp2_fast(float x) {
#if __has_builtin(__builtin_amdgcn_exp2f)
    return __builtin_amdgcn_exp2f(x);
#else
    float r; asm("v_exp_f32 %0, %1" : "=v"(r) : "v"(x)); return r;
#endif
}
__device__ __forceinline__ float xor16_f(float x) {
#if __has_builtin(__builtin_amdgcn_permlane16_swap)
    typedef unsigned uint2v __attribute__((ext_vector_type(2)));
    unsigned xi = __float_as_int(x);
    uint2v pr = __builtin_amdgcn_permlane16_swap(xi, xi, false, false);
    return (__uint_as_float(pr[0]) + __uint_as_float(pr[1])) - x;
#else
    return __int_as_float(
        __builtin_amdgcn_ds_swizzle(__float_as_int(x), 0x401F)); // xor 16
#endif
}

union FragU { unsigned u[4]; short8 s; };

__global__ __launch_bounds__(256, 4) void cmdnet_kernel(
    const float* __restrict__ yt,      // [B,64]
    const float* __restrict__ Ht,      // [B,64,32]
    const float* __restrict__ sigmat0, // [B]
    const float* __restrict__ taui,    // [niter+1]
    const float* __restrict__ delta,   // [niter]
    float* __restrict__ out_ft,        // [B,32,2]
    float* __restrict__ out_xt,        // [B,32]
    int niter)
{
    __shared__ __align__(16) float hhbuf[4][KSYM * KSYM]; // 16 KB: ONE region/wave
    __shared__ __align__(16) float ytL[4][4][NRX];        // 4 KB: 4 batches/wave

    const int tid  = threadIdx.x;
    const int w    = tid >> 6;
    const int lane = tid & 63;
    const int k    = lane & 31;
    const int h    = lane >> 5;
    const int hi8  = h * 8;
    const int bb   = blockIdx.x * 16 + w * 4;   // first of this wave's 4 batches
    const float LOG2E = 1.4426950408889634f;

    #pragma unroll
    for (int s = 0; s < 4; ++s)
        ytL[w][s][lane] = yt[(size_t)(bb + s) * NRX + lane];

    float dreg = 0.f, treg = 1.f;
    if (lane < niter) { dreg = delta[lane] * LOG2E; treg = fabsf(taui[lane + 1]); }

    const int bA = bb + h, bB = bb + 2 + h;
    float sig2A = sigmat0[bA]; sig2A *= sig2A;
    float sig2B = sigmat0[bB]; sig2B *= sig2B;

    float yhp0 = 0.f, yhp1 = 0.f, yhp2 = 0.f, yhp3 = 0.f;
    f32x16 acc;

    // ---- MFMA pass over batch slot S: acc = HH, yH partial (bf16 hi/lo) ----
    #define MFMA_PASS(S, YHP) do {                                             \
        _Pragma("unroll")                                                      \
        for (int j = 0; j < 16; ++j) acc[j] = 0.f;                             \
        const float* Hb = Ht + ((size_t)(bb + (S))) * (NRX * KSYM);            \
        _Pragma("unroll")                                                      \
        for (int c = 0; c < 4; ++c) {                                          \
            const float* base = Hb + (c * 16 + hi8) * KSYM + k;                \
            float f[8];                                                        \
            _Pragma("unroll")                                                  \
            for (int e = 0; e < 8; ++e) f[e] = base[e * KSYM];                 \
            float4 ya = *reinterpret_cast<const float4*>(&ytL[w][S][c*16+hi8]);\
            float4 yb = *reinterpret_cast<const float4*>(&ytL[w][S][c*16+hi8+4]);\
            YHP = fmaf(ya.x, f[0], YHP); YHP = fmaf(ya.y, f[1], YHP);          \
            YHP = fmaf(ya.z, f[2], YHP); YHP = fmaf(ya.w, f[3], YHP);          \
            YHP = fmaf(yb.x, f[4], YHP); YHP = fmaf(yb.y, f[5], YHP);          \
            YHP = fmaf(yb.z, f[6], YHP); YHP = fmaf(yb.w, f[7], YHP);          \
            FragU hiF, loF;                                                    \
            _Pragma("unroll")                                                  \
            for (int p = 0; p < 4; ++p) {                                      \
                unsigned hp = cvt_pk_bf16(f[2*p], f[2*p+1]);                   \
                float h0 = __uint_as_float(hp << 16);                          \
                float h1 = __uint_as_float(hp & 0xffff0000u);                  \
                loF.u[p] = cvt_pk_bf16(f[2*p] - h0, f[2*p+1] - h1);            \
                hiF.u[p] = hp;                                                 \
            }                                                                  \
            acc = __builtin_amdgcn_mfma_f32_32x32x16_bf16(hiF.s, hiF.s, acc, 0,0,0); \
            acc = __builtin_amdgcn_mfma_f32_32x32x16_bf16(hiF.s, loF.s, acc, 0,0,0); \
            acc = __builtin_amdgcn_mfma_f32_32x32x16_bf16(loF.s, hiF.s, acc, 0,0,0); \
        }                                                                      \
    } while (0)

    #define STORE_ACC() do {                                                   \
        _Pragma("unroll")                                                      \
        for (int j = 0; j < 16; ++j) {                                         \
            int row = (j & 3) + 8 * (j >> 2) + 4 * h;                          \
            hhbuf[w][row * 32 + k] = acc[j];                                   \
        }                                                                      \
    } while (0)

    #define GATH(DST, J) {                                                     \
        int idx = dpp_ror_i<J>(low4);                                          \
        DST[J] = cvt_pk_f16(0.5f * rowp[(k & 16) | idx],                       \
                            0.5f * rowp[((k & 16) ^ 16) | idx]); }
    #define GATHER(DST) do {                                                   \
        const float* rowp = &hhbuf[w][k * 32];                                 \
        const int low4 = k & 15;                                               \
        DST[0] = cvt_pk_f16(0.5f * rowp[k], 0.5f * rowp[k ^ 16]);              \
        GATH(DST, 1)  GATH(DST, 2)  GATH(DST, 3)  GATH(DST, 4)  GATH(DST, 5)  \
        GATH(DST, 6)  GATH(DST, 7)  GATH(DST, 8)  GATH(DST, 9)  GATH(DST, 10) \
        GATH(DST, 11) GATH(DST, 12) GATH(DST, 13) GATH(DST, 14) GATH(DST, 15) \
    } while (0)

    const bool hs = (h != 0);
    int own_pkA[16], own_pkB[16];

    // pair A = batches (bb, bb+1)
    MFMA_PASS(0, yhp0);
    STORE_ACC();
    MFMA_PASS(1, yhp1);
    {
        int g0[16], g1[16];
        GATHER(g0);                 // HH_{bb}
        STORE_ACC();
        GATHER(g1);                 // HH_{bb+1}
        #pragma unroll
        for (int j = 0; j < 16; ++j) own_pkA[j] = hs ? g1[j] : g0[j];
    }
    // pair B = batches (bb+2, bb+3)
    MFMA_PASS(2, yhp2);
    STORE_ACC();
    MFMA_PASS(3, yhp3);
    {
        int g2[16], g3[16];
        GATHER(g2);                 // HH_{bb+2}
        STORE_ACC();
        GATHER(g3);                 // HH_{bb+3}
        #pragma unroll
        for (int j = 0; j < 16; ++j) own_pkB[j] = hs ? g3[j] : g2[j];
    }

    float s0 = yhp0 + __shfl_xor(yhp0, 32, 64);
    float s1 = yhp1 + __shfl_xor(yhp1, 32, 64);
    float s2 = yhp2 + __shfl_xor(yhp2, 32, 64);
    float s3 = yhp3 + __shfl_xor(yhp3, 32, 64);
    float yhA = 0.5f * (hs ? s1 : s0);
    float yhB = 0.5f * (hs ? s3 : s2);

    // ---- iterations: two independent streams interleaved ----
    float tau = fabsf(taui[0]);
    float GA0 = 0.f, GA1 = 0.f, xtA = 0.f;
    float GB0 = 0.f, GB1 = 0.f, xtB = 0.f;

    for (int i = 0; i < niter; ++i) {
        float d2       = readlane_f(dreg, i);
        float tau_next = readlane_f(treg, i);

        float xtsA = xor16_f(xtA);
        float xtsB = xor16_f(xtB);
        int xpkA = cvt_pk_f16(xtA, xtsA);
        int xpkB = cvt_pk_f16(xtB, xtsB);

        float aA0 = -yhA, aA1 = 0.f, aA2 = 0.f, aA3 = 0.f;
        float aB0 = -yhB, aB1 = 0.f, aB2 = 0.f, aB3 = 0.f;
        aA0 = dot2_f16(own_pkA[0], xpkA, aA0);
        aB0 = dot2_f16(own_pkB[0], xpkB, aB0);
        #define STEP(J) {                                                      \
            int xrA = dpp_ror_i<J>(xpkA);                                      \
            int xrB = dpp_ror_i<J>(xpkB);                                      \
            float& uA = ((J) & 3) == 0 ? aA0 : ((J) & 3) == 1 ? aA1            \
                       : ((J) & 3) == 2 ? aA2 : aA3;                           \
            float& uB = ((J) & 3) == 0 ? aB0 : ((J) & 3) == 1 ? aB1            \
                       : ((J) & 3) == 2 ? aB2 : aB3;                           \
            uA = dot2_f16(own_pkA[J], xrA, uA);                                \
            uB = dot2_f16(own_pkB[J], xrB, uB); }
        STEP(1)  STEP(2)  STEP(3)  STEP(4)  STEP(5)
        STEP(6)  STEP(7)  STEP(8)  STEP(9)  STEP(10)
        STEP(11) STEP(12) STEP(13) STEP(14) STEP(15)
        #undef STEP
        float rA = (aA0 + aA1) + (aA2 + aA3);
        float rB = (aB0 + aB1) + (aB2 + aB3);

        float tA = fmaf(-xtA, xtA, 1.0f);
        float tB = fmaf(-xtB, xtB, 1.0f);
        float pA = tau * tA * rA;
        float pB = tau * tB * rB;
        float eA0 = exp2_fast(-GA0), eA1 = exp2_fast(-GA1);
        float eB0 = exp2_fast(-GB0), eB1 = exp2_fast(-GB1);
        float gA0 = fmaf(sig2A, 1.f - eA0, -pA);
        float gA1 = fmaf(sig2A, 1.f - eA1,  pA);
        float gB0 = fmaf(sig2B, 1.f - eB0, -pB);
        float gB1 = fmaf(sig2B, 1.f - eB1,  pB);
        GA0 = fmaf(-d2, gA0, GA0);
        GA1 = fmaf(-d2, gA1, GA1);
        GB0 = fmaf(-d2, gB0, GB0);
        GB1 = fmaf(-d2, gB1, GB1);

        tau = tau_next;
        float zA = tau * (GA1 - GA0);
        float zB = tau * (GB1 - GB0);
        float ezA = exp2_fast(-fabsf(zA));
        float ezB = exp2_fast(-fabsf(zB));
        float sgA = __builtin_amdgcn_rcpf(1.f + ezA);
        float sgB = __builtin_amdgcn_rcpf(1.f + ezB);
        float mA = (1.f - ezA) * sgA;
        float mB = (1.f - ezB) * sgB;
        xtA = __builtin_copysignf(mA, zA);
        xtB = __builtin_copysignf(mB, zB);
    }

    // ---- outputs ----
    float ftA1 = fmaf(0.5f, xtA, 0.5f);
    float ftB1 = fmaf(0.5f, xtB, 0.5f);
    reinterpret_cast<float2*>(out_ft)[(size_t)bA * KSYM + k] = make_float2(1.f - ftA1, ftA1);
    reinterpret_cast<float2*>(out_ft)[(size_t)bB * KSYM + k] = make_float2(1.f - ftB1, ftB1);
    out_xt[(size_t)bA * KSYM + k] = xtA;
    out_xt[(size_t)bB * KSYM + k] = xtB;
}

extern "C" void kernel_launch(void* const* d_in, const int* in_sizes, int n_in,
                              void* d_out, int out_size, void* d_ws, size_t ws_size,
                              hipStream_t stream) {
    const float* yt    = (const float*)d_in[0];
    const float* Ht    = (const float*)d_in[1];
    const float* sg    = (const float*)d_in[2];
    const float* taui  = (const float*)d_in[3];
    const float* delta = (const float*)d_in[4];
    int B     = in_sizes[2];
    int niter = in_sizes[4];
    float* out    = (float*)d_out;
    float* out_ft = out;
    float* out_xt = out + (size_t)B * 64;

    dim3 grid(B / 16), block(256);
    hipLaunchKernelGGL(cmdnet_kernel, grid, block, 0, stream,
                       yt, Ht, sg, taui, delta, out_ft, out_xt, niter);
}

// Round 14
// 77.301 us; speedup vs baseline: 1.1993x; 1.0536x over previous
//
#include <hip/hip_runtime.h>

// CMDNet (M=2, m={-1,+1}, equal alpha) — MFMA HH + dot2/DPP matvec.
// Base = R11 (78.3 us, proven): (256,4), two per-batch LDS regions, uniform
// post-phase-1 gather (no divergent long-lived defs), dot2-f16 matvec,
// permlane16_swap xor-16, exp2-domain G.
//
// R14 change: DPP rotate as ONE bare `v_mov_b32_dpp` via inline asm.
// __builtin_amdgcn_update_dpp(0, src, ...) ties dst to `old` -> compiler
// materializes a v_mov per rotate (15/iter on the hot path, ~20% of loop
// issue). Inline asm "=v"(dst) : "v"(src) has no tied/identical-value
// operands (R9 lesson audited: dst is write-only, src stays live).
// Probe (gather) and loop share the SAME macro -> layout agrees by
// construction. Also: e0/e1 hoisted ahead of matvec (depend only on
// previous-iter G) to shorten the post-matvec serial chain.
//
// Operating point: (256,4) FINAL (R2/R3/R5/R7/R8/R12: any waves/EU>4 ask
// spills; R13: fewer-waves ILP variant loses phase diversity).
// Tripwire: FETCH >> 68 MB or WRITE >> 6 MB => spill => revert.

#define NRX 64
#define KSYM 32

typedef float  f32x16 __attribute__((ext_vector_type(16)));
typedef short  short8 __attribute__((ext_vector_type(8)));
typedef _Float16 h16x2 __attribute__((ext_vector_type(2)));

__device__ __forceinline__ float readlane_f(float v, int lane) {
    return __int_as_float(__builtin_amdgcn_readlane(__float_as_int(v), lane));
}
__device__ __forceinline__ unsigned cvt_pk_bf16(float a, float b) {
    unsigned r;
    asm("v_cvt_pk_bf16_f32 %0, %1, %2" : "=v"(r) : "v"(a), "v"(b));
    return r;
}
__device__ __forceinline__ int cvt_pk_f16(float a, float b) {  // RTZ pack
    int r;
    asm("v_cvt_pkrtz_f16_f32 %0, %1, %2" : "=v"(r) : "v"(a), "v"(b));
    return r;
}
// ONE-instruction DPP rotate (see header comment). J must be a literal.
#define DPP_ROR(DST, SRC, J)                                                   \
    asm("v_mov_b32_dpp %0, %1 row_ror:" #J " row_mask:0xf bank_mask:0xf"       \
        : "=v"(DST) : "v"(SRC))

__device__ __forceinline__ float dot2_f16(int a, int b, float c) {
#if __has_builtin(__builtin_amdgcn_fdot2)
    union { int i; h16x2 h; } ua, ub;
    ua.i = a; ub.i = b;
    return __builtin_amdgcn_fdot2(ua.h, ub.h, c, false);
#else
    float r = c;
    asm("v_dot2_f32_f16 %0, %1, %2, %0" : "+v"(r) : "v"(a), "v"(b));
    return r;
#endif
}
__device__ __forceinline__ float exp2_fast(float x) {
#if __has_builtin(__builtin_amdgcn_exp2f)
    return __builtin_amdgcn_exp2f(x);
#else
    float r; asm("v_exp_f32 %0, %1" : "=v"(r) : "v"(x)); return r;
#endif
}
__device__ __forceinline__ float xor16_f(float x) {
#if __has_builtin(__builtin_amdgcn_permlane16_swap)
    typedef unsigned uint2v __attribute__((ext_vector_type(2)));
    unsigned xi = __float_as_int(x);
    uint2v pr = __builtin_amdgcn_permlane16_swap(xi, xi, false, false);
    return (__uint_as_float(pr[0]) + __uint_as_float(pr[1])) - x;
#else
    return __int_as_float(
        __builtin_amdgcn_ds_swizzle(__float_as_int(x), 0x401F)); // xor 16
#endif
}

union FragU { unsigned u[4]; short8 s; };

__global__ __launch_bounds__(256, 4) void cmdnet_kernel(
    const float* __restrict__ yt,      // [B,64]
    const float* __restrict__ Ht,      // [B,64,32]
    const float* __restrict__ sigmat0, // [B]
    const float* __restrict__ taui,    // [niter+1]
    const float* __restrict__ delta,   // [niter]
    float* __restrict__ out_ft,        // [B,32,2]
    float* __restrict__ out_xt,        // [B,32]
    int niter)
{
    __shared__ __align__(16) float hhbuf[4][2][KSYM * KSYM]; // 32 KB: per-wave, per-batch
    __shared__ __align__(16) float ytL[4][2][NRX];           // 2 KB

    const int tid  = threadIdx.x;
    const int w    = tid >> 6;
    const int lane = tid & 63;
    const int k    = lane & 31;
    const int h    = lane >> 5;
    const int hi8  = h * 8;
    const int bb   = blockIdx.x * 8 + w * 2;
    const int b    = bb + h;
    const float LOG2E = 1.4426950408889634f;

    ytL[w][0][lane] = yt[(size_t)bb * NRX + lane];
    ytL[w][1][lane] = yt[(size_t)bb * NRX + NRX + lane];

    // delta in exp2 domain; tau natural
    float dreg = 0.f, treg = 1.f;
    if (lane < niter) { dreg = delta[lane] * LOG2E; treg = fabsf(taui[lane + 1]); }

    float sig2 = sigmat0[b];
    sig2 *= sig2;

    float yhp0 = 0.f, yhp1 = 0.f;

    // ---- Phase 1: per batch s: MFMA HH (one shared acc) -> LDS region s ----
    #pragma unroll
    for (int s = 0; s < 2; ++s) {
        f32x16 acc;
        #pragma unroll
        for (int j = 0; j < 16; ++j) acc[j] = 0.f;

        const float* Hb = Ht + ((size_t)(bb + s)) * (NRX * KSYM);
        #pragma unroll
        for (int c = 0; c < 4; ++c) {
            const float* base = Hb + (c * 16 + hi8) * KSYM + k;
            float f[8];
            #pragma unroll
            for (int e = 0; e < 8; ++e) f[e] = base[e * KSYM];

            float4 ya = *reinterpret_cast<const float4*>(&ytL[w][s][c * 16 + hi8]);
            float4 yb = *reinterpret_cast<const float4*>(&ytL[w][s][c * 16 + hi8 + 4]);
            float yp = (s == 0) ? yhp0 : yhp1;
            yp = fmaf(ya.x, f[0], yp); yp = fmaf(ya.y, f[1], yp);
            yp = fmaf(ya.z, f[2], yp); yp = fmaf(ya.w, f[3], yp);
            yp = fmaf(yb.x, f[4], yp); yp = fmaf(yb.y, f[5], yp);
            yp = fmaf(yb.z, f[6], yp); yp = fmaf(yb.w, f[7], yp);
            if (s == 0) yhp0 = yp; else yhp1 = yp;

            FragU hiF, loF;
            #pragma unroll
            for (int p = 0; p < 4; ++p) {
                unsigned hp = cvt_pk_bf16(f[2*p], f[2*p+1]);
                float h0 = __uint_as_float(hp << 16);
                float h1 = __uint_as_float(hp & 0xffff0000u);
                loF.u[p] = cvt_pk_bf16(f[2*p] - h0, f[2*p+1] - h1);
                hiF.u[p] = hp;
            }
            acc = __builtin_amdgcn_mfma_f32_32x32x16_bf16(hiF.s, hiF.s, acc, 0, 0, 0);
            acc = __builtin_amdgcn_mfma_f32_32x32x16_bf16(hiF.s, loF.s, acc, 0, 0, 0);
            acc = __builtin_amdgcn_mfma_f32_32x32x16_bf16(loF.s, hiF.s, acc, 0, 0, 0);
        }

        // acc -> LDS region s (C/D layout: col=lane&31, row=(j&3)+8*(j>>2)+4*h)
        float* buf_s = &hhbuf[w][s][0];
        #pragma unroll
        for (int j = 0; j < 16; ++j) {
            int row = (j & 3) + 8 * (j >> 2) + 4 * h;
            buf_s[row * 32 + k] = acc[j];
        }
    }

    // ---- Phase 2: UNIFORM gather: lane (h,k) reads its row from region h,
    //      diagonal-permuted with the SAME DPP_ROR macro as the loop,
    //      scaled by 0.5, packed f16.
    int own_pk[16];
    {
        const int low4 = k & 15;
        const float* rowp = &hhbuf[w][h][k * 32];
        own_pk[0] = cvt_pk_f16(0.5f * rowp[k], 0.5f * rowp[k ^ 16]);
        #define GATH(J) { \
            int idx; DPP_ROR(idx, low4, J); \
            own_pk[J] = cvt_pk_f16(0.5f * rowp[(k & 16) | idx], \
                                   0.5f * rowp[((k & 16) ^ 16) | idx]); }
        GATH(1)  GATH(2)  GATH(3)  GATH(4)  GATH(5)
        GATH(6)  GATH(7)  GATH(8)  GATH(9)  GATH(10)
        GATH(11) GATH(12) GATH(13) GATH(14) GATH(15)
        #undef GATH
    }

    float yh0 = yhp0 + __shfl_xor(yhp0, 32, 64);
    float yh1 = yhp1 + __shfl_xor(yhp1, 32, 64);
    float yh  = 0.5f * (h ? yh1 : yh0);   // pre-halved to match own_pk scale

    // ---- Phase 3: iterations ----
    float tau = fabsf(taui[0]);
    float Gl0 = 0.f, Gl1 = 0.f;           // G * log2e
    float xt = 0.f;

    for (int i = 0; i < niter; ++i) {
        float d2       = readlane_f(dreg, i);   // delta*log2e
        float tau_next = readlane_f(treg, i);

        // e0/e1 depend only on previous-iter G: issue before the matvec so
        // the quarter-rate trans ops overlap the dot2 chain.
        float e0 = exp2_fast(-Gl0);        // = exp(-G0)
        float e1 = exp2_fast(-Gl1);

        float xts = xor16_f(xt);
        int xpk = cvt_pk_f16(xt, xts);

        float a0 = -yh, a1 = 0.f, a2 = 0.f, a3 = 0.f;
        a0 = dot2_f16(own_pk[0], xpk, a0);
        #define STEP(J) {                                                      \
            int xr; DPP_ROR(xr, xpk, J);                                       \
            float& aa = ((J) & 3) == 0 ? a0 : ((J) & 3) == 1 ? a1              \
                       : ((J) & 3) == 2 ? a2 : a3;                             \
            aa = dot2_f16(own_pk[J], xr, aa); }
        STEP(1)  STEP(2)  STEP(3)  STEP(4)  STEP(5)
        STEP(6)  STEP(7)  STEP(8)  STEP(9)  STEP(10)
        STEP(11) STEP(12) STEP(13) STEP(14) STEP(15)
        #undef STEP
        float r = (a0 + a1) + (a2 + a3);   // = 0.5*(xHH - yH)

        float t  = fmaf(-xt, xt, 1.0f);
        float p  = tau * t * r;            // = 2*tau*ft0*ft1*(xHH-yH)
        float g0 = fmaf(sig2, 1.f - e0, -p);
        float g1 = fmaf(sig2, 1.f - e1,  p);
        Gl0 = fmaf(-d2, g0, Gl0);
        Gl1 = fmaf(-d2, g1, Gl1);

        tau = tau_next;
        float z2 = tau * (Gl1 - Gl0);      // = log2e * z
        float ez = exp2_fast(-fabsf(z2));  // = exp(-|z|)
        float sg = __builtin_amdgcn_rcpf(1.f + ez);
        float m  = (1.f - ez) * sg;        // |tanh(z/2)|
        xt = __builtin_copysignf(m, z2);
    }

    // ---- outputs: ft1 = (1+xt)/2, ft0 = (1-xt)/2 ----
    float ft1 = fmaf(0.5f, xt, 0.5f);
    float ft0 = 1.f - ft1;
    float2 f2 = make_float2(ft0, ft1);
    reinterpret_cast<float2*>(out_ft)[(size_t)b * KSYM + k] = f2;
    out_xt[(size_t)b * KSYM + k] = xt;
}

extern "C" void kernel_launch(void* const* d_in, const int* in_sizes, int n_in,
                              void* d_out, int out_size, void* d_ws, size_t ws_size,
                              hipStream_t stream) {
    const float* yt    = (const float*)d_in[0];
    const float* Ht    = (const float*)d_in[1];
    const float* sg    = (const float*)d_in[2];
    const float* taui  = (const float*)d_in[3];
    const float* delta = (const float*)d_in[4];
    int B     = in_sizes[2];
    int niter = in_sizes[4];
    float* out    = (float*)d_out;
    float* out_ft = out;
    float* out_xt = out + (size_t)B * 64;

    dim3 grid(B / 8), block(256);
    hipLaunchKernelGGL(cmdnet_kernel, grid, block, 0, stream,
                       yt, Ht, sg, taui, delta, out_ft, out_xt, niter);
}